// Round 8
// baseline (30.418 us; speedup 1.0000x reference)
//
#include <hip/hip_runtime.h>
#include <math.h>

// Problem shape (fixed by setup_inputs)
#define Bb 2
#define Vv 3
#define Nn 4096
#define NDIR 16
#define NRB 16            // rowblock slots; x2 slices covers 4096 rows worst-case
#define RPB 128           // rows per slice
#define NBLKS (NDIR*NRB)  // 256
#define PADW 1.5e38f

// ws (uint view): [0..255] partial bits, [256..511] ~partial bits

__device__ __forceinline__ void slots_for_dir(int dir, int* sA, int* sB){
    int k = dir & 3, bi = dir >> 2, b = bi >> 1;
    switch (k){
        case 0:  *sA = b;       *sB = 6 + bi;  break;  // fwd d_ab: rows ref, cols p2r
        case 1:  *sA = 6 + bi;  *sB = b;       break;  // fwd d_ba
        case 2:  *sA = 2 + bi;  *sB = 10 + bi; break;  // bwd d_ab: rows tgt, cols r2t
        default: *sA = 10 + bi; *sB = 2 + bi;  break;  // bwd d_ba
    }
}

// slot -> (b, view for depth/mask, M[9], tv[3]) ; point = M*(x,y,1)*d + tv
__device__ __forceinline__ void build_matrix(int slot,
                                             const float* __restrict__ poses,
                                             const float* __restrict__ intr,
                                             float* M, float* tv, int* bOut, int* vOut){
    int type, b, im1;
    if (slot < 2)      { type = 0; b = slot;         im1 = 0; }
    else if (slot < 6) { type = 1; b = (slot-2)>>1;  im1 = (slot-2)&1; }
    else if (slot < 10){ type = 2; b = (slot-6)>>1;  im1 = (slot-6)&1; }
    else               { type = 3; b = (slot-10)>>1; im1 = (slot-10)&1; }
    int vi = im1 + 1;
    *bOut = b;
    *vOut = (type==0 || type==3) ? 0 : vi;

    const float* Km = intr + b*9;
    float ka=Km[0],kb=Km[1],kc=Km[2],kd=Km[3],ke=Km[4],kf=Km[5],kg=Km[6],kh=Km[7],ki=Km[8];
    float c00=(ke*ki-kf*kh), c10=-(kd*ki-kf*kg), c20=(kd*kh-ke*kg);
    float det = ka*c00 + kb*c10 + kc*c20, iv = 1.0f/det;
    float Ki[9] = { c00*iv, -(kb*ki-kc*kh)*iv,  (kb*kf-kc*ke)*iv,
                    c10*iv,  (ka*ki-kc*kg)*iv, -(ka*kf-kc*kd)*iv,
                    c20*iv, -(ka*kh-kb*kg)*iv,  (ka*ke-kb*kd)*iv };
    tv[0] = tv[1] = tv[2] = 0.f;
    if (type < 2){
        #pragma unroll
        for (int i = 0; i < 9; ++i) M[i] = Ki[i];
        return;
    }
    const float* P0 = poses + (b*Vv + 0)*16;
    const float* Pi = poses + (b*Vv + vi)*16;
    float R[9];
    if (type == 2){  // inv(pose0) @ pose_i
        #pragma unroll
        for (int r = 0; r < 3; ++r){
            #pragma unroll
            for (int c = 0; c < 3; ++c)
                R[r*3+c] = P0[0*4+r]*Pi[0*4+c] + P0[1*4+r]*Pi[1*4+c] + P0[2*4+r]*Pi[2*4+c];
            tv[r] = P0[0*4+r]*(Pi[3]-P0[3]) + P0[1*4+r]*(Pi[7]-P0[7]) + P0[2*4+r]*(Pi[11]-P0[11]);
        }
    } else {         // inv(pose_i) @ pose0
        #pragma unroll
        for (int r = 0; r < 3; ++r){
            #pragma unroll
            for (int c = 0; c < 3; ++c)
                R[r*3+c] = Pi[0*4+r]*P0[0*4+c] + Pi[1*4+r]*P0[1*4+c] + Pi[2*4+r]*P0[2*4+c];
            tv[r] = Pi[0*4+r]*(P0[3]-Pi[3]) + Pi[1*4+r]*(P0[7]-Pi[7]) + Pi[2*4+r]*(P0[11]-Pi[11]);
        }
    }
    #pragma unroll
    for (int r = 0; r < 3; ++r)
        #pragma unroll
        for (int c = 0; c < 3; ++c)
            M[r*3+c] = R[r*3+0]*Ki[0*3+c] + R[r*3+1]*Ki[1*3+c] + R[r*3+2]*Ki[2*3+c];
}

// Single fused kernel: 256 blocks (16 dirs x 16 rowblks, 2-slice guard), 8-row
// register blocking, scalar fmaf/max3 inner loop, self-validating publish,
// block-0 deterministic finish.
__global__ void __launch_bounds__(256) fused_kernel(const float* __restrict__ poses,
                                                    const float* __restrict__ masks,
                                                    const float* __restrict__ intr,
                                                    const float* __restrict__ depth,
                                                    float* __restrict__ ws,
                                                    float* __restrict__ out){
    __shared__ float4 sB[Nn + 32];   // 66 KB, AoS (x,y,z, 0.5|p|^2)
    __shared__ float4 sA[RPB];
    __shared__ int   wsum[4];
    __shared__ float sred[16];
    __shared__ float fred[4];

    int bid = blockIdx.x;
    int dir    = bid & (NDIR-1);
    int rowblk = bid >> 4;           // 0..15
    int slotA, slotB;
    slots_for_dir(dir, &slotA, &slotB);

    int tid = threadIdx.x;
    int lane = tid & 63, wv = tid >> 6;

    float MA[9], tA[3], MB[9], tB[3];
    int b, vA, vB, bdummy;
    build_matrix(slotA, poses, intr, MA, tA, &b, &vA);
    build_matrix(slotB, poses, intr, MB, tB, &bdummy, &vB);

    // ---- A scan: flags + depth stash + prefix -> base, cntA ----
    unsigned flA = 0; int tsA = 0;
    float dvA[16];
    {
        const float* mb = masks + (b*Vv + vA)*Nn + tid*16;
        const float* db = depth + (b*Vv + vA)*Nn + tid*16;
        #pragma unroll
        for (int q = 0; q < 4; ++q){
            float4 m4 = *(const float4*)(mb + q*4);
            float4 d4 = *(const float4*)(db + q*4);
            const float* mv = (const float*)&m4;
            const float* dd = (const float*)&d4;
            #pragma unroll
            for (int r = 0; r < 4; ++r){
                dvA[q*4+r] = dd[r];
                if (mv[r] > 0.5f){ flA |= 1u << (q*4 + r); ++tsA; }
            }
        }
    }
    int inc = tsA;
    #pragma unroll
    for (int off = 1; off < 64; off <<= 1){
        int t = __shfl_up(inc, off, 64);
        if (lane >= off) inc += t;
    }
    if (lane == 63) wsum[wv] = inc;
    __syncthreads();
    int base = inc - tsA;
    #pragma unroll
    for (int w = 0; w < 4; ++w) if (w < wv) base += wsum[w];
    int cntA = wsum[0] + wsum[1] + wsum[2] + wsum[3];
    __syncthreads();   // wsum reuse

    // ---- B scan + compacted AoS build ----
    unsigned flB = 0; int tsB = 0;
    float dv[16];
    {
        const float* mb = masks + (b*Vv + vB)*Nn + tid*16;
        const float* db = depth + (b*Vv + vB)*Nn + tid*16;
        #pragma unroll
        for (int q = 0; q < 4; ++q){
            float4 m4 = *(const float4*)(mb + q*4);
            float4 d4 = *(const float4*)(db + q*4);
            const float* mv = (const float*)&m4;
            const float* dd = (const float*)&d4;
            #pragma unroll
            for (int r = 0; r < 4; ++r){
                dv[q*4+r] = dd[r];
                if (mv[r] > 0.5f){ flB |= 1u << (q*4 + r); ++tsB; }
            }
        }
    }
    int incB = tsB;
    #pragma unroll
    for (int off = 1; off < 64; off <<= 1){
        int t = __shfl_up(incB, off, 64);
        if (lane >= off) incB += t;
    }
    if (lane == 63) wsum[wv] = incB;
    __syncthreads();
    int baseB = incB - tsB;
    #pragma unroll
    for (int w = 0; w < 4; ++w) if (w < wv) baseB += wsum[w];
    int cntB = wsum[0] + wsum[1] + wsum[2] + wsum[3];

    {
        int p = baseB;
        #pragma unroll
        for (int k = 0; k < 16; ++k){
            if (flB & (1u << k)){
                int n = tid*16 + k;
                float d = dv[k];
                float x = (float)(n & 63), y = (float)(n >> 6);
                float ux = fmaf(MB[0],x, fmaf(MB[1],y, MB[2]));
                float uy = fmaf(MB[3],x, fmaf(MB[4],y, MB[5]));
                float uz = fmaf(MB[6],x, fmaf(MB[7],y, MB[8]));
                float px = fmaf(ux,d,tB[0]), py = fmaf(uy,d,tB[1]), pz = fmaf(uz,d,tB[2]);
                sB[p++] = make_float4(px, py, pz, 0.5f*(px*px + py*py + pz*pz));
            }
        }
    }
    int cntBp = (cntB + 31) & ~31;
    for (int t = cntB + tid; t < cntBp; t += 256)
        sB[t] = make_float4(0.f, 0.f, 0.f, PADW);

    float tsum = 0.f;   // tid 0 accumulates across slices

    // ---- slices: rowblk and rowblk+16 (second skipped unless cntA > 2048) ----
    for (int s = rowblk; s < 32; s += 16){
        int lo = s * RPB;
        int nRows = min(cntA - lo, RPB);
        if (nRows <= 0) break;       // uniform

        // write this slice's A rows
        {
            int p = base;
            #pragma unroll
            for (int k = 0; k < 16; ++k){
                if (flA & (1u << k)){
                    int rel = p - lo;
                    if (rel >= 0 && rel < RPB){
                        int n = tid*16 + k;
                        float d = dvA[k];
                        float x = (float)(n & 63), y = (float)(n >> 6);
                        float ux = fmaf(MA[0],x, fmaf(MA[1],y, MA[2]));
                        float uy = fmaf(MA[3],x, fmaf(MA[4],y, MA[5]));
                        float uz = fmaf(MA[6],x, fmaf(MA[7],y, MA[8]));
                        float px = fmaf(ux,d,tA[0]), py = fmaf(uy,d,tA[1]), pz = fmaf(uz,d,tA[2]);
                        sA[rel] = make_float4(px,py,pz, 0.5f*(px*px+py*py+pz*pz));
                    }
                    ++p;
                }
            }
        }
        __syncthreads();

        // ---- pair loop: 16 rowgrps x 8 rows, 16 colparts x 2 cols ----
        int rowgrp = tid >> 4, colpart = tid & 15;
        int rbase = rowgrp * 8;
        float4 a[8];
        #pragma unroll
        for (int r = 0; r < 8; ++r) a[r] = sA[rbase + r];
        float m[8];
        #pragma unroll
        for (int r = 0; r < 8; ++r) m[r] = -3.0e38f;

        int nIter = cntBp >> 5;
        const float4* sb0 = sB + colpart;
        for (int j = 0; j < nIter; ++j){
            float4 c0 = sb0[32*j];
            float4 c1 = sb0[32*j + 16];
            #pragma unroll
            for (int r = 0; r < 8; ++r){
                float u0 = fmaf(a[r].z,c0.z, fmaf(a[r].y,c0.y, fmaf(a[r].x,c0.x, -c0.w)));
                float u1 = fmaf(a[r].z,c1.z, fmaf(a[r].y,c1.y, fmaf(a[r].x,c1.x, -c1.w)));
                m[r] = fmaxf(fmaxf(u0, u1), m[r]);   // v_max3
            }
        }
        // exact per-row max over 16 colparts
        #pragma unroll
        for (int off = 1; off < 16; off <<= 1){
            #pragma unroll
            for (int r = 0; r < 8; ++r)
                m[r] = fmaxf(m[r], __shfl_xor(m[r], off, 64));
        }
        if (colpart == 0){
            float sl = 0.f;
            #pragma unroll
            for (int r = 0; r < 8; ++r)
                if (rbase + r < nRows) sl += 2.0f*(a[r].w - m[r]);
            sred[rowgrp] = sl;
        }
        __syncthreads();
        if (tid == 0){
            #pragma unroll
            for (int g = 0; g < 16; ++g) tsum += sred[g];
        }
        __syncthreads();   // sA/sred reuse in next slice
    }

    // ---- publish self-validating pair (bits, ~bits) ----
    unsigned* wsu = (unsigned*)ws;
    if (tid == 0){
        float partial = tsum / (fmaxf((float)cntA, 1.0f) * 16.0f);
        unsigned pb = __float_as_uint(partial);
        atomicExch(&wsu[bid], pb);
        atomicExch(&wsu[NBLKS + bid], ~pb);
    }
    if (bid != 0) return;

    // ---- block 0: wait for all 256 consistent pairs, fixed-order sum ----
    __syncthreads();
    unsigned va, vb;
    for (;;){
        va = atomicAdd(&wsu[tid], 0u);
        vb = atomicAdd(&wsu[NBLKS + tid], 0u);
        if (va == ~vb) break;
        __builtin_amdgcn_s_sleep(1);
    }
    float v = __uint_as_float(va);
    for (int off = 32; off > 0; off >>= 1) v += __shfl_down(v, off, 64);
    if (lane == 0) fred[wv] = v;
    __syncthreads();
    if (tid == 0) out[0] = fred[0] + fred[1] + fred[2] + fred[3];
}

extern "C" void kernel_launch(void* const* d_in, const int* in_sizes, int n_in,
                              void* d_out, int out_size, void* d_ws, size_t ws_size,
                              hipStream_t stream) {
    // inputs: 0 views (unused), 1 poses, 2 masks, 3 intrinsics, 4 depth_maps, 5 num_views
    const float* poses = (const float*)d_in[1];
    const float* masks = (const float*)d_in[2];
    const float* intr  = (const float*)d_in[3];
    const float* depth = (const float*)d_in[4];
    float* ws  = (float*)d_ws;
    float* out = (float*)d_out;

    fused_kernel<<<NBLKS, 256, 0, stream>>>(poses, masks, intr, depth, ws, out);
}

// Round 9
// 25.117 us; speedup vs baseline: 1.2111x; 1.2111x over previous
//
#include <hip/hip_runtime.h>
#include <math.h>

// Problem shape (fixed by setup_inputs)
#define Bb 2
#define Vv 3
#define Nn 4096
#define NDIR 16
#define NRB 32            // rowblocks per dir (dynamic row split)
#define NBLKS (NDIR*NRB)  // 512
#define PADW 1.5e38f

// ws (uint view): [0..511] partial bits, [512..1023] ~partial bits

__device__ __forceinline__ void slots_for_dir(int dir, int* sA, int* sB){
    int k = dir & 3, bi = dir >> 2, b = bi >> 1;
    switch (k){
        case 0:  *sA = b;       *sB = 6 + bi;  break;  // fwd d_ab: rows ref, cols p2r
        case 1:  *sA = 6 + bi;  *sB = b;       break;  // fwd d_ba
        case 2:  *sA = 2 + bi;  *sB = 10 + bi; break;  // bwd d_ab: rows tgt, cols r2t
        default: *sA = 10 + bi; *sB = 2 + bi;  break;  // bwd d_ba
    }
}

// slot -> (b, view for depth/mask, M[9], tv[3]) ; point = M*(x,y,1)*d + tv
__device__ __forceinline__ void build_matrix(int slot,
                                             const float* __restrict__ poses,
                                             const float* __restrict__ intr,
                                             float* M, float* tv, int* bOut, int* vOut){
    int type, b, im1;
    if (slot < 2)      { type = 0; b = slot;         im1 = 0; }
    else if (slot < 6) { type = 1; b = (slot-2)>>1;  im1 = (slot-2)&1; }
    else if (slot < 10){ type = 2; b = (slot-6)>>1;  im1 = (slot-6)&1; }
    else               { type = 3; b = (slot-10)>>1; im1 = (slot-10)&1; }
    int vi = im1 + 1;
    *bOut = b;
    *vOut = (type==0 || type==3) ? 0 : vi;

    const float* Km = intr + b*9;
    float ka=Km[0],kb=Km[1],kc=Km[2],kd=Km[3],ke=Km[4],kf=Km[5],kg=Km[6],kh=Km[7],ki=Km[8];
    float c00=(ke*ki-kf*kh), c10=-(kd*ki-kf*kg), c20=(kd*kh-ke*kg);
    float det = ka*c00 + kb*c10 + kc*c20, iv = 1.0f/det;
    float Ki[9] = { c00*iv, -(kb*ki-kc*kh)*iv,  (kb*kf-kc*ke)*iv,
                    c10*iv,  (ka*ki-kc*kg)*iv, -(ka*kf-kc*kd)*iv,
                    c20*iv, -(ka*kh-kb*kg)*iv,  (ka*ke-kb*kd)*iv };
    tv[0] = tv[1] = tv[2] = 0.f;
    if (type < 2){
        #pragma unroll
        for (int i = 0; i < 9; ++i) M[i] = Ki[i];
        return;
    }
    const float* P0 = poses + (b*Vv + 0)*16;
    const float* Pi = poses + (b*Vv + vi)*16;
    float R[9];
    if (type == 2){  // inv(pose0) @ pose_i
        #pragma unroll
        for (int r = 0; r < 3; ++r){
            #pragma unroll
            for (int c = 0; c < 3; ++c)
                R[r*3+c] = P0[0*4+r]*Pi[0*4+c] + P0[1*4+r]*Pi[1*4+c] + P0[2*4+r]*Pi[2*4+c];
            tv[r] = P0[0*4+r]*(Pi[3]-P0[3]) + P0[1*4+r]*(Pi[7]-P0[7]) + P0[2*4+r]*(Pi[11]-P0[11]);
        }
    } else {         // inv(pose_i) @ pose0
        #pragma unroll
        for (int r = 0; r < 3; ++r){
            #pragma unroll
            for (int c = 0; c < 3; ++c)
                R[r*3+c] = Pi[0*4+r]*P0[0*4+c] + Pi[1*4+r]*P0[1*4+c] + Pi[2*4+r]*P0[2*4+c];
            tv[r] = Pi[0*4+r]*(P0[3]-Pi[3]) + Pi[1*4+r]*(P0[7]-Pi[7]) + Pi[2*4+r]*(P0[11]-Pi[11]);
        }
    }
    #pragma unroll
    for (int r = 0; r < 3; ++r)
        #pragma unroll
        for (int c = 0; c < 3; ++c)
            M[r*3+c] = R[r*3+0]*Ki[0*3+c] + R[r*3+1]*Ki[1*3+c] + R[r*3+2]*Ki[2*3+c];
}

// R5 structure + dynamic row partitioning + wave-level trip gating.
__global__ void __launch_bounds__(256) fused_kernel(const float* __restrict__ poses,
                                                    const float* __restrict__ masks,
                                                    const float* __restrict__ intr,
                                                    const float* __restrict__ depth,
                                                    float* __restrict__ ws,
                                                    float* __restrict__ out){
    __shared__ float4 sB[Nn + 16];   // 66 KB AoS (x,y,z, 0.5|p|^2)
    __shared__ float4 sA[128];
    __shared__ int   wsum[4];
    __shared__ float sred[32];
    __shared__ float fred[4];

    int bid = blockIdx.x;
    int rowblk = bid & (NRB-1);
    int dir    = bid >> 5;
    int slotA, slotB;
    slots_for_dir(dir, &slotA, &slotB);

    int tid = threadIdx.x;
    int lane = tid & 63, wv = tid >> 6;

    float MA[9], tA[3], MB[9], tB[3];
    int b, vA, vB, bdummy;
    build_matrix(slotA, poses, intr, MA, tA, &b, &vA);
    build_matrix(slotB, poses, intr, MB, tB, &bdummy, &vB);

    // ---- A phase: mask scan (+depth stash) for cntA and this block's slice ----
    unsigned flA = 0; int tsA = 0;
    float dvA[16];
    {
        const float* mb = masks + (b*Vv + vA)*Nn + tid*16;
        const float* db = depth + (b*Vv + vA)*Nn + tid*16;
        #pragma unroll
        for (int q = 0; q < 4; ++q){
            float4 m4 = *(const float4*)(mb + q*4);
            float4 d4 = *(const float4*)(db + q*4);
            const float* mv = (const float*)&m4;
            const float* dd = (const float*)&d4;
            #pragma unroll
            for (int r = 0; r < 4; ++r){
                dvA[q*4+r] = dd[r];
                if (mv[r] > 0.5f){ flA |= 1u << (q*4 + r); ++tsA; }
            }
        }
    }
    int inc = tsA;
    #pragma unroll
    for (int off = 1; off < 64; off <<= 1){
        int t = __shfl_up(inc, off, 64);
        if (lane >= off) inc += t;
    }
    if (lane == 63) wsum[wv] = inc;
    __syncthreads();
    int base = inc - tsA;
    #pragma unroll
    for (int w = 0; w < 4; ++w) if (w < wv) base += wsum[w];
    int cntA = wsum[0] + wsum[1] + wsum[2] + wsum[3];

    // dynamic row split: every block gets ~cntA/32 rows (<=128)
    int nper = (cntA + NRB - 1) >> 5;
    int lo = rowblk * nper;
    int nRows = min(cntA - lo, nper);
    float partial = 0.f;

    if (nRows > 0){
        // write this block's A rows (compacted indices [lo, lo+nRows))
        {
            int p = base;
            #pragma unroll
            for (int k = 0; k < 16; ++k){
                if (flA & (1u << k)){
                    int rel = p - lo;
                    if (rel >= 0 && rel < nRows){
                        int n = tid*16 + k;
                        float d = dvA[k];
                        float x = (float)(n & 63), y = (float)(n >> 6);
                        float ux = fmaf(MA[0],x, fmaf(MA[1],y, MA[2]));
                        float uy = fmaf(MA[3],x, fmaf(MA[4],y, MA[5]));
                        float uz = fmaf(MA[6],x, fmaf(MA[7],y, MA[8]));
                        float px = fmaf(ux,d,tA[0]), py = fmaf(uy,d,tA[1]), pz = fmaf(uz,d,tA[2]);
                        sA[rel] = make_float4(px,py,pz, 0.5f*(px*px+py*py+pz*pz));
                    }
                    ++p;
                }
            }
        }
        if (tid < 32) sred[tid] = 0.f;
        __syncthreads();   // A writes + sred init done; wsum free for reuse

        // ---- B phase: full compacted cloud into LDS (AoS) ----
        unsigned flB = 0; int tsB = 0;
        float dv[16];
        {
            const float* mb = masks + (b*Vv + vB)*Nn + tid*16;
            const float* db = depth + (b*Vv + vB)*Nn + tid*16;
            #pragma unroll
            for (int q = 0; q < 4; ++q){
                float4 m4 = *(const float4*)(mb + q*4);
                float4 d4 = *(const float4*)(db + q*4);
                const float* mv = (const float*)&m4;
                const float* dd = (const float*)&d4;
                #pragma unroll
                for (int r = 0; r < 4; ++r){
                    dv[q*4+r] = dd[r];
                    if (mv[r] > 0.5f){ flB |= 1u << (q*4 + r); ++tsB; }
                }
            }
        }
        int incB = tsB;
        #pragma unroll
        for (int off = 1; off < 64; off <<= 1){
            int t = __shfl_up(incB, off, 64);
            if (lane >= off) incB += t;
        }
        if (lane == 63) wsum[wv] = incB;
        __syncthreads();
        int baseB = incB - tsB;
        #pragma unroll
        for (int w = 0; w < 4; ++w) if (w < wv) baseB += wsum[w];
        int cntB = wsum[0] + wsum[1] + wsum[2] + wsum[3];

        {
            int p = baseB;
            #pragma unroll
            for (int k = 0; k < 16; ++k){
                if (flB & (1u << k)){
                    int n = tid*16 + k;
                    float d = dv[k];
                    float x = (float)(n & 63), y = (float)(n >> 6);
                    float ux = fmaf(MB[0],x, fmaf(MB[1],y, MB[2]));
                    float uy = fmaf(MB[3],x, fmaf(MB[4],y, MB[5]));
                    float uz = fmaf(MB[6],x, fmaf(MB[7],y, MB[8]));
                    float px = fmaf(ux,d,tB[0]), py = fmaf(uy,d,tB[1]), pz = fmaf(uz,d,tB[2]);
                    sB[p++] = make_float4(px, py, pz, 0.5f*(px*px + py*py + pz*pz));
                }
            }
        }
        int cntBp = (cntB + 15) & ~15;
        if (tid < cntBp - cntB) sB[cntB + tid] = make_float4(0.f, 0.f, 0.f, PADW);
        __syncthreads();

        // ---- pair loop: 32 rowgrps (4 rows) x 8 colparts; wave-gated by nRows ----
        int rowgrp = tid >> 3, colpart = tid & 7;
        int rbase = rowgrp * 4;
        if (wv * 32 < nRows){            // wave-uniform: skip all-garbage waves
            float4 a0 = sA[rbase+0], a1 = sA[rbase+1], a2 = sA[rbase+2], a3 = sA[rbase+3];
            float m0 = -3.0e38f, m1 = -3.0e38f, m2 = -3.0e38f, m3 = -3.0e38f;

            int nIter = cntBp >> 4;
            const float4* sbp = sB + colpart;
            #pragma unroll 2
            for (int j = 0; j < nIter; ++j){
                float4 c0 = sbp[16*j];
                float4 c1 = sbp[16*j + 8];
                float u00 = fmaf(a0.z,c0.z, fmaf(a0.y,c0.y, fmaf(a0.x,c0.x, -c0.w)));
                float u01 = fmaf(a0.z,c1.z, fmaf(a0.y,c1.y, fmaf(a0.x,c1.x, -c1.w)));
                float u10 = fmaf(a1.z,c0.z, fmaf(a1.y,c0.y, fmaf(a1.x,c0.x, -c0.w)));
                float u11 = fmaf(a1.z,c1.z, fmaf(a1.y,c1.y, fmaf(a1.x,c1.x, -c1.w)));
                float u20 = fmaf(a2.z,c0.z, fmaf(a2.y,c0.y, fmaf(a2.x,c0.x, -c0.w)));
                float u21 = fmaf(a2.z,c1.z, fmaf(a2.y,c1.y, fmaf(a2.x,c1.x, -c1.w)));
                float u30 = fmaf(a3.z,c0.z, fmaf(a3.y,c0.y, fmaf(a3.x,c0.x, -c0.w)));
                float u31 = fmaf(a3.z,c1.z, fmaf(a3.y,c1.y, fmaf(a3.x,c1.x, -c1.w)));
                m0 = fmaxf(fmaxf(u00, u01), m0);   // v_max3
                m1 = fmaxf(fmaxf(u10, u11), m1);
                m2 = fmaxf(fmaxf(u20, u21), m2);
                m3 = fmaxf(fmaxf(u30, u31), m3);
            }
            #pragma unroll
            for (int off = 1; off < 8; off <<= 1){
                m0 = fmaxf(m0, __shfl_xor(m0, off, 64));
                m1 = fmaxf(m1, __shfl_xor(m1, off, 64));
                m2 = fmaxf(m2, __shfl_xor(m2, off, 64));
                m3 = fmaxf(m3, __shfl_xor(m3, off, 64));
            }
            if (colpart == 0){
                float s = 0.f;
                if (rbase + 0 < nRows) s += 2.0f*(a0.w - m0);
                if (rbase + 1 < nRows) s += 2.0f*(a1.w - m1);
                if (rbase + 2 < nRows) s += 2.0f*(a2.w - m2);
                if (rbase + 3 < nRows) s += 2.0f*(a3.w - m3);
                sred[rowgrp] = s;
            }
        }
        __syncthreads();
        if (tid == 0){
            float tsum = 0.f;
            #pragma unroll
            for (int g = 0; g < 32; ++g) tsum += sred[g];
            partial = tsum / (fmaxf((float)cntA, 1.0f) * 16.0f);
        }
    }

    // ---- publish self-validating pair (bits, ~bits) ----
    unsigned* wsu = (unsigned*)ws;
    if (tid == 0){
        unsigned pb = __float_as_uint(partial);
        atomicExch(&wsu[bid], pb);
        atomicExch(&wsu[NBLKS + bid], ~pb);
    }
    if (bid != 0) return;

    // ---- block 0: wait for all 512 consistent pairs, fixed-order sum ----
    __syncthreads();
    float p0, p1;
    {
        unsigned va, vb;
        for (;;){
            va = atomicAdd(&wsu[tid], 0u);
            vb = atomicAdd(&wsu[NBLKS + tid], 0u);
            if (va == ~vb) break;
            __builtin_amdgcn_s_sleep(1);
        }
        p0 = __uint_as_float(va);
        for (;;){
            va = atomicAdd(&wsu[tid + 256], 0u);
            vb = atomicAdd(&wsu[NBLKS + tid + 256], 0u);
            if (va == ~vb) break;
            __builtin_amdgcn_s_sleep(1);
        }
        p1 = __uint_as_float(va);
    }
    float v = p0 + p1;
    for (int off = 32; off > 0; off >>= 1) v += __shfl_down(v, off, 64);
    if (lane == 0) fred[wv] = v;
    __syncthreads();
    if (tid == 0) out[0] = fred[0] + fred[1] + fred[2] + fred[3];
}

extern "C" void kernel_launch(void* const* d_in, const int* in_sizes, int n_in,
                              void* d_out, int out_size, void* d_ws, size_t ws_size,
                              hipStream_t stream) {
    // inputs: 0 views (unused), 1 poses, 2 masks, 3 intrinsics, 4 depth_maps, 5 num_views
    const float* poses = (const float*)d_in[1];
    const float* masks = (const float*)d_in[2];
    const float* intr  = (const float*)d_in[3];
    const float* depth = (const float*)d_in[4];
    float* ws  = (float*)d_ws;
    float* out = (float*)d_out;

    fused_kernel<<<NBLKS, 256, 0, stream>>>(poses, masks, intr, depth, ws, out);
}

// Round 10
// 23.951 us; speedup vs baseline: 1.2700x; 1.0487x over previous
//
#include <hip/hip_runtime.h>
#include <math.h>

// Problem shape (fixed by setup_inputs)
#define Bb 2
#define Vv 3
#define Nn 4096
#define NDIR 16
#define NRB 32            // rowblocks per dir (dynamic row split)
#define NBLKS (NDIR*NRB)  // 512
#define PADW 1.5e38f

// ws (u64 view): entry i at wsp[8*i] (64B stride) = (~bits<<32)|bits of partial i

__device__ __forceinline__ void slots_for_dir(int dir, int* sA, int* sB){
    int k = dir & 3, bi = dir >> 2, b = bi >> 1;
    switch (k){
        case 0:  *sA = b;       *sB = 6 + bi;  break;  // fwd d_ab: rows ref, cols p2r
        case 1:  *sA = 6 + bi;  *sB = b;       break;  // fwd d_ba
        case 2:  *sA = 2 + bi;  *sB = 10 + bi; break;  // bwd d_ab: rows tgt, cols r2t
        default: *sA = 10 + bi; *sB = 2 + bi;  break;  // bwd d_ba
    }
}

// slot -> (b, view for depth/mask, M[9], tv[3]) ; point = M*(x,y,1)*d + tv
__device__ __forceinline__ void build_matrix(int slot,
                                             const float* __restrict__ poses,
                                             const float* __restrict__ intr,
                                             float* M, float* tv, int* bOut, int* vOut){
    int type, b, im1;
    if (slot < 2)      { type = 0; b = slot;         im1 = 0; }
    else if (slot < 6) { type = 1; b = (slot-2)>>1;  im1 = (slot-2)&1; }
    else if (slot < 10){ type = 2; b = (slot-6)>>1;  im1 = (slot-6)&1; }
    else               { type = 3; b = (slot-10)>>1; im1 = (slot-10)&1; }
    int vi = im1 + 1;
    *bOut = b;
    *vOut = (type==0 || type==3) ? 0 : vi;

    const float* Km = intr + b*9;
    float ka=Km[0],kb=Km[1],kc=Km[2],kd=Km[3],ke=Km[4],kf=Km[5],kg=Km[6],kh=Km[7],ki=Km[8];
    float c00=(ke*ki-kf*kh), c10=-(kd*ki-kf*kg), c20=(kd*kh-ke*kg);
    float det = ka*c00 + kb*c10 + kc*c20, iv = 1.0f/det;
    float Ki[9] = { c00*iv, -(kb*ki-kc*kh)*iv,  (kb*kf-kc*ke)*iv,
                    c10*iv,  (ka*ki-kc*kg)*iv, -(ka*kf-kc*kd)*iv,
                    c20*iv, -(ka*kh-kb*kg)*iv,  (ka*ke-kb*kd)*iv };
    tv[0] = tv[1] = tv[2] = 0.f;
    if (type < 2){
        #pragma unroll
        for (int i = 0; i < 9; ++i) M[i] = Ki[i];
        return;
    }
    const float* P0 = poses + (b*Vv + 0)*16;
    const float* Pi = poses + (b*Vv + vi)*16;
    float R[9];
    if (type == 2){  // inv(pose0) @ pose_i
        #pragma unroll
        for (int r = 0; r < 3; ++r){
            #pragma unroll
            for (int c = 0; c < 3; ++c)
                R[r*3+c] = P0[0*4+r]*Pi[0*4+c] + P0[1*4+r]*Pi[1*4+c] + P0[2*4+r]*Pi[2*4+c];
            tv[r] = P0[0*4+r]*(Pi[3]-P0[3]) + P0[1*4+r]*(Pi[7]-P0[7]) + P0[2*4+r]*(Pi[11]-P0[11]);
        }
    } else {         // inv(pose_i) @ pose0
        #pragma unroll
        for (int r = 0; r < 3; ++r){
            #pragma unroll
            for (int c = 0; c < 3; ++c)
                R[r*3+c] = Pi[0*4+r]*P0[0*4+c] + Pi[1*4+r]*P0[1*4+c] + Pi[2*4+r]*P0[2*4+c];
            tv[r] = Pi[0*4+r]*(P0[3]-Pi[3]) + Pi[1*4+r]*(P0[7]-Pi[7]) + Pi[2*4+r]*(P0[11]-Pi[11]);
        }
    }
    #pragma unroll
    for (int r = 0; r < 3; ++r)
        #pragma unroll
        for (int c = 0; c < 3; ++c)
            M[r*3+c] = R[r*3+0]*Ki[0*3+c] + R[r*3+1]*Ki[1*3+c] + R[r*3+2]*Ki[2*3+c];
}

// R8 structure; publish = single u64 atomicExch per block, 64B-padded slots.
__global__ void __launch_bounds__(256) fused_kernel(const float* __restrict__ poses,
                                                    const float* __restrict__ masks,
                                                    const float* __restrict__ intr,
                                                    const float* __restrict__ depth,
                                                    float* __restrict__ ws,
                                                    float* __restrict__ out){
    __shared__ float4 sB[Nn + 16];   // 66 KB AoS (x,y,z, 0.5|p|^2)
    __shared__ float4 sA[128];
    __shared__ int   wsum[4];
    __shared__ float sred[32];
    __shared__ float fred[4];

    int bid = blockIdx.x;
    int rowblk = bid & (NRB-1);
    int dir    = bid >> 5;
    int slotA, slotB;
    slots_for_dir(dir, &slotA, &slotB);

    int tid = threadIdx.x;
    int lane = tid & 63, wv = tid >> 6;

    float MA[9], tA[3], MB[9], tB[3];
    int b, vA, vB, bdummy;
    build_matrix(slotA, poses, intr, MA, tA, &b, &vA);
    build_matrix(slotB, poses, intr, MB, tB, &bdummy, &vB);

    // ---- A phase: mask scan (+depth stash) for cntA and this block's slice ----
    unsigned flA = 0; int tsA = 0;
    float dvA[16];
    {
        const float* mb = masks + (b*Vv + vA)*Nn + tid*16;
        const float* db = depth + (b*Vv + vA)*Nn + tid*16;
        #pragma unroll
        for (int q = 0; q < 4; ++q){
            float4 m4 = *(const float4*)(mb + q*4);
            float4 d4 = *(const float4*)(db + q*4);
            const float* mv = (const float*)&m4;
            const float* dd = (const float*)&d4;
            #pragma unroll
            for (int r = 0; r < 4; ++r){
                dvA[q*4+r] = dd[r];
                if (mv[r] > 0.5f){ flA |= 1u << (q*4 + r); ++tsA; }
            }
        }
    }
    int inc = tsA;
    #pragma unroll
    for (int off = 1; off < 64; off <<= 1){
        int t = __shfl_up(inc, off, 64);
        if (lane >= off) inc += t;
    }
    if (lane == 63) wsum[wv] = inc;
    __syncthreads();
    int base = inc - tsA;
    #pragma unroll
    for (int w = 0; w < 4; ++w) if (w < wv) base += wsum[w];
    int cntA = wsum[0] + wsum[1] + wsum[2] + wsum[3];

    // dynamic row split: every block gets ~cntA/32 rows (<=128)
    int nper = (cntA + NRB - 1) >> 5;
    int lo = rowblk * nper;
    int nRows = min(cntA - lo, nper);
    float partial = 0.f;

    if (nRows > 0){
        // write this block's A rows (compacted indices [lo, lo+nRows))
        {
            int p = base;
            #pragma unroll
            for (int k = 0; k < 16; ++k){
                if (flA & (1u << k)){
                    int rel = p - lo;
                    if (rel >= 0 && rel < nRows){
                        int n = tid*16 + k;
                        float d = dvA[k];
                        float x = (float)(n & 63), y = (float)(n >> 6);
                        float ux = fmaf(MA[0],x, fmaf(MA[1],y, MA[2]));
                        float uy = fmaf(MA[3],x, fmaf(MA[4],y, MA[5]));
                        float uz = fmaf(MA[6],x, fmaf(MA[7],y, MA[8]));
                        float px = fmaf(ux,d,tA[0]), py = fmaf(uy,d,tA[1]), pz = fmaf(uz,d,tA[2]);
                        sA[rel] = make_float4(px,py,pz, 0.5f*(px*px+py*py+pz*pz));
                    }
                    ++p;
                }
            }
        }
        if (tid < 32) sred[tid] = 0.f;
        __syncthreads();   // A writes + sred init done; wsum free for reuse

        // ---- B phase: full compacted cloud into LDS (AoS) ----
        unsigned flB = 0; int tsB = 0;
        float dv[16];
        {
            const float* mb = masks + (b*Vv + vB)*Nn + tid*16;
            const float* db = depth + (b*Vv + vB)*Nn + tid*16;
            #pragma unroll
            for (int q = 0; q < 4; ++q){
                float4 m4 = *(const float4*)(mb + q*4);
                float4 d4 = *(const float4*)(db + q*4);
                const float* mv = (const float*)&m4;
                const float* dd = (const float*)&d4;
                #pragma unroll
                for (int r = 0; r < 4; ++r){
                    dv[q*4+r] = dd[r];
                    if (mv[r] > 0.5f){ flB |= 1u << (q*4 + r); ++tsB; }
                }
            }
        }
        int incB = tsB;
        #pragma unroll
        for (int off = 1; off < 64; off <<= 1){
            int t = __shfl_up(incB, off, 64);
            if (lane >= off) incB += t;
        }
        if (lane == 63) wsum[wv] = incB;
        __syncthreads();
        int baseB = incB - tsB;
        #pragma unroll
        for (int w = 0; w < 4; ++w) if (w < wv) baseB += wsum[w];
        int cntB = wsum[0] + wsum[1] + wsum[2] + wsum[3];

        {
            int p = baseB;
            #pragma unroll
            for (int k = 0; k < 16; ++k){
                if (flB & (1u << k)){
                    int n = tid*16 + k;
                    float d = dv[k];
                    float x = (float)(n & 63), y = (float)(n >> 6);
                    float ux = fmaf(MB[0],x, fmaf(MB[1],y, MB[2]));
                    float uy = fmaf(MB[3],x, fmaf(MB[4],y, MB[5]));
                    float uz = fmaf(MB[6],x, fmaf(MB[7],y, MB[8]));
                    float px = fmaf(ux,d,tB[0]), py = fmaf(uy,d,tB[1]), pz = fmaf(uz,d,tB[2]);
                    sB[p++] = make_float4(px, py, pz, 0.5f*(px*px + py*py + pz*pz));
                }
            }
        }
        int cntBp = (cntB + 15) & ~15;
        if (tid < cntBp - cntB) sB[cntB + tid] = make_float4(0.f, 0.f, 0.f, PADW);
        __syncthreads();

        // ---- pair loop: 32 rowgrps (4 rows) x 8 colparts; wave-gated by nRows ----
        int rowgrp = tid >> 3, colpart = tid & 7;
        int rbase = rowgrp * 4;
        if (wv * 32 < nRows){            // wave-uniform: skip all-garbage waves
            float4 a0 = sA[rbase+0], a1 = sA[rbase+1], a2 = sA[rbase+2], a3 = sA[rbase+3];
            float m0 = -3.0e38f, m1 = -3.0e38f, m2 = -3.0e38f, m3 = -3.0e38f;

            int nIter = cntBp >> 4;
            const float4* sbp = sB + colpart;
            #pragma unroll 2
            for (int j = 0; j < nIter; ++j){
                float4 c0 = sbp[16*j];
                float4 c1 = sbp[16*j + 8];
                float u00 = fmaf(a0.z,c0.z, fmaf(a0.y,c0.y, fmaf(a0.x,c0.x, -c0.w)));
                float u01 = fmaf(a0.z,c1.z, fmaf(a0.y,c1.y, fmaf(a0.x,c1.x, -c1.w)));
                float u10 = fmaf(a1.z,c0.z, fmaf(a1.y,c0.y, fmaf(a1.x,c0.x, -c0.w)));
                float u11 = fmaf(a1.z,c1.z, fmaf(a1.y,c1.y, fmaf(a1.x,c1.x, -c1.w)));
                float u20 = fmaf(a2.z,c0.z, fmaf(a2.y,c0.y, fmaf(a2.x,c0.x, -c0.w)));
                float u21 = fmaf(a2.z,c1.z, fmaf(a2.y,c1.y, fmaf(a2.x,c1.x, -c1.w)));
                float u30 = fmaf(a3.z,c0.z, fmaf(a3.y,c0.y, fmaf(a3.x,c0.x, -c0.w)));
                float u31 = fmaf(a3.z,c1.z, fmaf(a3.y,c1.y, fmaf(a3.x,c1.x, -c1.w)));
                m0 = fmaxf(fmaxf(u00, u01), m0);   // v_max3
                m1 = fmaxf(fmaxf(u10, u11), m1);
                m2 = fmaxf(fmaxf(u20, u21), m2);
                m3 = fmaxf(fmaxf(u30, u31), m3);
            }
            #pragma unroll
            for (int off = 1; off < 8; off <<= 1){
                m0 = fmaxf(m0, __shfl_xor(m0, off, 64));
                m1 = fmaxf(m1, __shfl_xor(m1, off, 64));
                m2 = fmaxf(m2, __shfl_xor(m2, off, 64));
                m3 = fmaxf(m3, __shfl_xor(m3, off, 64));
            }
            if (colpart == 0){
                float s = 0.f;
                if (rbase + 0 < nRows) s += 2.0f*(a0.w - m0);
                if (rbase + 1 < nRows) s += 2.0f*(a1.w - m1);
                if (rbase + 2 < nRows) s += 2.0f*(a2.w - m2);
                if (rbase + 3 < nRows) s += 2.0f*(a3.w - m3);
                sred[rowgrp] = s;
            }
        }
        __syncthreads();
        if (tid == 0){
            float tsum = 0.f;
            #pragma unroll
            for (int g = 0; g < 32; ++g) tsum += sred[g];
            partial = tsum / (fmaxf((float)cntA, 1.0f) * 16.0f);
        }
    }

    // ---- publish: ONE u64 atomicExch per block, own 64B line ----
    unsigned long long* wsp = (unsigned long long*)ws;
    if (tid == 0){
        unsigned pb = __float_as_uint(partial);
        unsigned long long pk = ((unsigned long long)(~pb) << 32) | (unsigned long long)pb;
        atomicExch(&wsp[8*bid], pk);
    }
    if (bid != 0) return;

    // ---- block 0: wait for all 512 consistent u64s, fixed-order sum ----
    __syncthreads();
    float p0, p1;
    {
        unsigned long long v;
        for (;;){
            v = atomicAdd(&wsp[8*tid], 0ull);
            unsigned lob = (unsigned)v, hib = (unsigned)(v >> 32);
            if (lob == ~hib) break;
            __builtin_amdgcn_s_sleep(1);
        }
        p0 = __uint_as_float((unsigned)v);
        for (;;){
            v = atomicAdd(&wsp[8*(tid + 256)], 0ull);
            unsigned lob = (unsigned)v, hib = (unsigned)(v >> 32);
            if (lob == ~hib) break;
            __builtin_amdgcn_s_sleep(1);
        }
        p1 = __uint_as_float((unsigned)v);
    }
    float v = p0 + p1;
    for (int off = 32; off > 0; off >>= 1) v += __shfl_down(v, off, 64);
    if (lane == 0) fred[wv] = v;
    __syncthreads();
    if (tid == 0) out[0] = fred[0] + fred[1] + fred[2] + fred[3];
}

extern "C" void kernel_launch(void* const* d_in, const int* in_sizes, int n_in,
                              void* d_out, int out_size, void* d_ws, size_t ws_size,
                              hipStream_t stream) {
    // inputs: 0 views (unused), 1 poses, 2 masks, 3 intrinsics, 4 depth_maps, 5 num_views
    const float* poses = (const float*)d_in[1];
    const float* masks = (const float*)d_in[2];
    const float* intr  = (const float*)d_in[3];
    const float* depth = (const float*)d_in[4];
    float* ws  = (float*)d_ws;
    float* out = (float*)d_out;

    fused_kernel<<<NBLKS, 256, 0, stream>>>(poses, masks, intr, depth, ws, out);
}